// Round 8
// baseline (68.233 us; speedup 1.0000x reference)
//
#include <hip/hip_runtime.h>
#include <math.h>

#define LOG2E 1.4426950408889634f
#define LN2   0.6931471805599453f

static constexpr int M  = 1024;
static constexpr int N  = 65536;
static constexpr int SB = 128;     // samples per block

typedef short bf16x8 __attribute__((ext_vector_type(8)));
typedef float f32x4  __attribute__((ext_vector_type(4)));

__device__ inline float wave_max64(float v) {
    #pragma unroll
    for (int o = 32; o > 0; o >>= 1) v = fmaxf(v, __shfl_xor(v, o));
    return v;
}
__device__ inline float wave_sum64(float v) {
    #pragma unroll
    for (int o = 32; o > 0; o >>= 1) v += __shfl_xor(v, o);
    return v;
}

// pack: low16 = bf16(a), high16 = bf16(b) (truncation)
__device__ inline unsigned pk2(float a, float b) {
    return (__float_as_uint(a) >> 16) | (__float_as_uint(b) & 0xFFFF0000u);
}
__device__ inline float truncbf(float f) {
    return __uint_as_float(__float_as_uint(f) & 0xFFFF0000u);
}

// 512 blocks x 1024 threads, 2 blocks/CU (8 waves/SIMD).
// R7 model confirmed twice: issue-serial @ ~1.2GHz DVFS clock; trans floor
// ~= 1024 wave-exps/SIMD. R8 overlaps the per-block staging/epilogue residue
// across co-resident blocks and dedups the hi/lo LDS staging:
//   coef row: [hi(4 uints) | lo(4) | pad(4)]  read offset (ksl>>1)*4
//   feat row: [fh | fl | pad]                 read offset (ksl&1)*4
// k-slice pairing preserved from R7 exactly: ksl 0:(hi,fh) 1:(hi,fl)
// 2:(lo,fh) 3:(lo,fl) -> (ch+cl)(fh+fl) exact cross-product.
// Stride 12 uints: b128 row starts 12r%32 -> 8 distinct banks x2 = 2-way (free).
__global__ __launch_bounds__(1024, 8)
void gm_all(const float* __restrict__ sample,
            const float* __restrict__ mu,
            const float* __restrict__ A,
            const float* __restrict__ w,
            float* __restrict__ out) {
    __shared__ __align__(16) unsigned coefL[M*12];    // 48 KiB
    __shared__ __align__(16) unsigned featL[SB*12];   // 6 KiB
    __shared__ float partial[16*SB];                  // 8 KiB  (62 total)

    const int t    = threadIdx.x;
    const int lane = t & 63;
    const int wv   = t >> 6;
    const int base = blockIdx.x * SB;

    // ---------- stage features: t<256 -> sample t>>1, hi/lo t&1 ----------
    if (t < 2*SB) {
        const int  s  = t >> 1;
        const bool lo = t & 1;
        const float2 p = ((const float2*)sample)[base + s];
        const float x = p.x - 0.5f, y = p.y - 0.5f;
        const float f0 = 1.0f, f1 = x, f2 = y, f3 = x*x, f4 = x*y, f5 = y*y;
        const float v0 = lo ? (f0 - truncbf(f0)) : f0;
        const float v1 = lo ? (f1 - truncbf(f1)) : f1;
        const float v2 = lo ? (f2 - truncbf(f2)) : f2;
        const float v3 = lo ? (f3 - truncbf(f3)) : f3;
        const float v4 = lo ? (f4 - truncbf(f4)) : f4;
        const float v5 = lo ? (f5 - truncbf(f5)) : f5;
        uint4 q;
        q.x = pk2(v0, v1); q.y = pk2(v2, v3); q.z = pk2(v4, v5); q.w = 0u;
        *(uint4*)&featL[s*12 + (lo ? 4 : 0)] = q;
    }

    // ---------- stage coefs: thread t -> comp t ----------
    {
        const float4 a4 = ((const float4*)A)[t];      // A00,A01,A10,A11
        const float2 m2 = ((const float2*)mu)[t];
        const float  wt = w[t];
        const float g00 = a4.x*a4.x + a4.y*a4.y;
        const float g01 = a4.x*a4.z + a4.y*a4.w;
        const float g11 = a4.z*a4.z + a4.w*a4.w;
        const float gm0 = g00*m2.x + g01*m2.y;
        const float gm1 = g01*m2.x + g11*m2.y;
        const float mGm = gm0*m2.x + gm1*m2.y;
        const float det = g00*g11 - g01*g01;
        const float t2  = wt*LOG2E + 0.5f*__builtin_amdgcn_logf(det);
        // original basis
        const float c0o = t2 - LOG2E*mGm;
        const float c1o = LOG2E*2.0f*gm0;
        const float c2o = LOG2E*2.0f*gm1;
        const float c3  = -LOG2E*g00;
        const float c4  = -LOG2E*2.0f*g01;
        const float c5  = -LOG2E*g11;
        // shift to x' = x-0.5 basis
        const float c1 = c1o + c3 + 0.5f*c4;
        const float c2 = c2o + c5 + 0.5f*c4;
        const float c0 = c0o + 0.5f*(c1o + c2o) + 0.25f*(c3 + c4 + c5);
        // hi/lo split
        const unsigned h0 = pk2(c0, c1), h1 = pk2(c2, c3), h2 = pk2(c4, c5);
        const float l0 = c0 - truncbf(c0), l1 = c1 - truncbf(c1);
        const float l2 = c2 - truncbf(c2), l3 = c3 - truncbf(c3);
        const float l4 = c4 - truncbf(c4), l5 = c5 - truncbf(c5);
        const uint4 hi4 = {h0, h1, h2, 0u};
        const uint4 lo4 = {pk2(l0, l1), pk2(l2, l3), pk2(l4, l5), 0u};
        *(uint4*)&coefL[t*12 + 0] = hi4;
        *(uint4*)&coefL[t*12 + 4] = lo4;
    }

    // ---------- w logsumexp: waves 0-1 only (their t<128 use nlse) ----------
    float nlse = 0.0f;
    if (wv < 2) {
        float4 wq[4];
        #pragma unroll
        for (int i = 0; i < 4; ++i)
            wq[i] = ((const float4*)w)[lane + 64*i];
        float wmax = wq[0].x;
        #pragma unroll
        for (int i = 0; i < 4; ++i) {
            wmax = fmaxf(wmax, wq[i].x); wmax = fmaxf(wmax, wq[i].y);
            wmax = fmaxf(wmax, wq[i].z); wmax = fmaxf(wmax, wq[i].w);
        }
        wmax = wave_max64(wmax);
        float sw = 0.0f;
        #pragma unroll
        for (int i = 0; i < 4; ++i) {
            sw += __builtin_amdgcn_exp2f((wq[i].x - wmax)*LOG2E);
            sw += __builtin_amdgcn_exp2f((wq[i].y - wmax)*LOG2E);
            sw += __builtin_amdgcn_exp2f((wq[i].z - wmax)*LOG2E);
            sw += __builtin_amdgcn_exp2f((wq[i].w - wmax)*LOG2E);
        }
        sw = wave_sum64(sw);
        nlse = -(wmax*LOG2E + __builtin_amdgcn_logf(sw));
    }

    __syncthreads();

    // ---------- main: per wave, 4 comp-tiles x 8 sample-tiles ----------
    const int l15 = lane & 15;        // A row (comp) / B,D col (sample)
    const int ksl = lane >> 4;        // k-slice: (coef hi/lo, feat hi/lo)
    bf16x8 aA[4];
    #pragma unroll
    for (int ct = 0; ct < 4; ++ct)
        aA[ct] = *(const bf16x8*)&coefL[(wv*64 + ct*16 + l15)*12 + (ksl >> 1)*4];

    const f32x4 zero4 = {0.0f, 0.0f, 0.0f, 0.0f};
    for (int st = 0; st < 8; ++st) {
        const bf16x8 bB = *(const bf16x8*)&featL[(st*16 + l15)*12 + (ksl & 1)*4];
        f32x4 d0 = __builtin_amdgcn_mfma_f32_16x16x32_bf16(aA[0], bB, zero4, 0, 0, 0);
        f32x4 d1 = __builtin_amdgcn_mfma_f32_16x16x32_bf16(aA[1], bB, zero4, 0, 0, 0);
        f32x4 d2 = __builtin_amdgcn_mfma_f32_16x16x32_bf16(aA[2], bB, zero4, 0, 0, 0);
        f32x4 d3 = __builtin_amdgcn_mfma_f32_16x16x32_bf16(aA[3], bB, zero4, 0, 0, 0);
        float s0 = (__builtin_amdgcn_exp2f(d0[0]) + __builtin_amdgcn_exp2f(d0[1]))
                 + (__builtin_amdgcn_exp2f(d0[2]) + __builtin_amdgcn_exp2f(d0[3]));
        float s1 = (__builtin_amdgcn_exp2f(d1[0]) + __builtin_amdgcn_exp2f(d1[1]))
                 + (__builtin_amdgcn_exp2f(d1[2]) + __builtin_amdgcn_exp2f(d1[3]));
        float s2 = (__builtin_amdgcn_exp2f(d2[0]) + __builtin_amdgcn_exp2f(d2[1]))
                 + (__builtin_amdgcn_exp2f(d2[2]) + __builtin_amdgcn_exp2f(d2[3]));
        float s3 = (__builtin_amdgcn_exp2f(d3[0]) + __builtin_amdgcn_exp2f(d3[1]))
                 + (__builtin_amdgcn_exp2f(d3[2]) + __builtin_amdgcn_exp2f(d3[3]));
        float s = (s0 + s1) + (s2 + s3);   // this lane: 16 comps, 1 sample
        s += __shfl_xor(s, 16);            // combine the 4 k-slice groups
        s += __shfl_xor(s, 32);
        if (ksl == 0) partial[wv*SB + st*16 + l15] = s;
    }

    __syncthreads();

    if (t < SB) {
        float ssum = partial[t];
        #pragma unroll
        for (int i = 1; i < 16; ++i) ssum += partial[i*SB + t];
        out[base + t] = LN2 * (nlse + __builtin_amdgcn_logf(ssum));
    }
}

extern "C" void kernel_launch(void* const* d_in, const int* in_sizes, int n_in,
                              void* d_out, int out_size, void* d_ws, size_t ws_size,
                              hipStream_t stream) {
    const float* sample = (const float*)d_in[0];
    const float* mu     = (const float*)d_in[1];
    const float* A      = (const float*)d_in[2];
    const float* w      = (const float*)d_in[3];
    float* out = (float*)d_out;
    (void)in_sizes; (void)n_in; (void)out_size; (void)d_ws; (void)ws_size;

    gm_all<<<N/SB, 1024, 0, stream>>>(sample, mu, A, w, out);
}